// Round 20
// baseline (27.119 us; speedup 1.0000x reference)
//
#include <hip/hip_runtime.h>
#include <hip/hip_bf16.h>
#include <math.h>

#define MAXP 32
#define PPW  4    // pillars per wave (2 independent pairs; proven optimum)
#define WPB  16   // waves per block (THE one change: 8 -> 16, HW max block)

typedef __attribute__((ext_vector_type(8)))  short bf16x8;
typedef __attribute__((ext_vector_type(16))) float f32x16;

template <int CTRL>
__device__ __forceinline__ float dppadd(float v) {
    int t = __builtin_amdgcn_update_dpp(0, __float_as_int(v), CTRL, 0xF, 0xF, false);
    return v + __int_as_float(t);
}
// sum within each 16-lane group (HW-verified R6-R19)
__device__ __forceinline__ float sum16(float v) {
    v = dppadd<0xB1>(v);    // xor1
    v = dppadd<0x4E>(v);    // xor2
    v = dppadd<0x141>(v);   // row_half_mirror
    v = dppadd<0x140>(v);   // row_mirror
    return v;
}
// within-32-half full sum from 16-group sums (HW-validated R13/R14)
__device__ __forceinline__ float fold16(float s) {
    auto pr = __builtin_amdgcn_permlane16_swap(__float_as_uint(s),
                                               __float_as_uint(s), false, false);
    return __uint_as_float(pr[0]) + __uint_as_float(pr[1]);
}
__device__ __forceinline__ float rdf(float v, int l) {
    return __int_as_float(__builtin_amdgcn_readlane(__float_as_int(v), l));
}
__device__ __forceinline__ int rdi(int v, int l) {
    return __builtin_amdgcn_readlane(v, l);
}
// HW-validated (R13/R14): permlane32_swap(a,b) -> pr[0]={a.lo,b.lo}, pr[1]={a.hi,b.hi}
__device__ __forceinline__ int swaphalf(int v) {   // other half's word into LO lanes
    auto pr = __builtin_amdgcn_permlane32_swap(v, v, false, false);
    return (int)pr[1];
}
__device__ __forceinline__ float mergemax(float mL, float mH) {
    auto pm = __builtin_amdgcn_permlane32_swap(__float_as_uint(mL),
                                               __float_as_uint(mH), false, false);
    return fmaxf(__uint_as_float(pm[0]), __uint_as_float(pm[1]));
}
// own-channel word -> (lo-half duplicated, hi-half duplicated) across all lanes
__device__ __forceinline__ void bothdup(int own, int& loAll, int& hiAll) {
    auto pr = __builtin_amdgcn_permlane32_swap(own, own, false, false);
    loAll = (int)pr[0];
    hiAll = (int)pr[1];
}
// 1-instruction bf16 pair pack (lo -> low16, hi -> high16); proven R10
__device__ __forceinline__ int cvtpk(float lo, float hi) {
    int r;
    asm("v_cvt_pk_bf16_f32 %0, %1, %2" : "=v"(r) : "v"(lo), "v"(hi));
    return r;
}
__device__ __forceinline__ float rmax16(f32x16 a) {   // max3-fusable tree
    float m1 = fmaxf(fmaxf(a[0], a[1]),  a[2]);
    float m2 = fmaxf(fmaxf(a[3], a[4]),  a[5]);
    float m3 = fmaxf(fmaxf(a[6], a[7]),  a[8]);
    float m4 = fmaxf(fmaxf(a[9], a[10]), a[11]);
    float m5 = fmaxf(fmaxf(a[12],a[13]), a[14]);
    float mm = fmaxf(fmaxf(m1, m2), m3);
    return fmaxf(fmaxf(fmaxf(m4, m5), a[15]), mm);
}

union FragAB { bf16x8 v; int i[4]; };

__global__ __launch_bounds__(WPB * 64) void pfn_kernel(
    const float* __restrict__ voxels,
    const int*   __restrict__ num_points,
    const int*   __restrict__ coords,
    const float* __restrict__ W,
    const float* __restrict__ gammav,
    const float* __restrict__ betav,
    const float* __restrict__ rmean,
    const float* __restrict__ rvar,
    float*       __restrict__ out,
    int N)
{
    const int  lane = threadIdx.x & 63;
    const int  wid  = threadIdx.x >> 6;   // 0..WPB-1
    const int  pt   = lane & 31;          // A-frag row (point slot)
    const bool lo32 = (lane < 32);

    int vz;                               // opaque 0: pins meta loads to VMEM
    asm("v_mov_b32 %0, 0" : "=v"(vz));

    const int base = (blockIdx.x * WPB + wid) * PPW;
    if (base >= N) return;

    // ---- setup: ONE coefficient block (own channel = lane), permlane-duplicated
    //      into both B-frags (content-identical; proven R18/R19) ----
    float P4s, P5s, P6s, P7s, P8s, shs;   // own channel's epilogue coefs
    FragAB fbL, fbH;                      // B-frags: only k=0..3 matter
    {
        const int c = lane;
        float w0=W[c],w1=W[64+c],w2=W[128+c],w3=W[192+c],w4=W[256+c],
              w5=W[320+c],w6=W[384+c],w7=W[448+c],w8=W[512+c];
        float inv = gammav[c] * rsqrtf(rvar[c] + 1e-3f);
        shs = fmaf(-rmean[c], inv, betav[c]);
        float A  =(w0+w4+w7)*inv, B=(w1+w5+w8)*inv, C=(w2+w6)*inv, Dk=w3*inv;
        P4s=w4*inv; P5s=w5*inv; P6s=w6*inv; P7s=w7*inv; P8s=w8*inv;
        const int own0 = cvtpk(A, B);
        const int own1 = cvtpk(C, Dk);
        bothdup(own0, fbL.i[0], fbH.i[0]);
        bothdup(own1, fbL.i[1], fbH.i[1]);
        fbL.i[2]=0; fbL.i[3]=0; fbH.i[2]=0; fbH.i[3]=0;
    }

    const f32x16 zacc = {0,0,0,0,0,0,0,0,0,0,0,0,0,0,0,0};

#define LOADPAIR(G, NPA, C0A, C1A, NPB, C0B, C1B, pA) do {                     \
    const int sA_ = min((pA),     N - 1);                                      \
    const int sB_ = min((pA) + 1, N - 1);                                      \
    const int sel_ = lo32 ? sA_ : sB_;                                         \
    G   = *(const float4*)((const char*)voxels +                               \
                           (size_t)sel_ * 512 + (size_t)pt * 16);              \
    NPA = *(const int*)((const char*)num_points + (size_t)sA_*4  + vz);        \
    C0A = *(const int*)((const char*)coords     + (size_t)sA_*12 + vz);        \
    C1A = *(const int*)((const char*)coords     + (size_t)sA_*12 + 4 + vz);    \
    NPB = *(const int*)((const char*)num_points + (size_t)sB_*4  + vz);        \
    C0B = *(const int*)((const char*)coords     + (size_t)sB_*12 + vz);        \
    C1B = *(const int*)((const char*)coords     + (size_t)sB_*12 + 4 + vz);    \
} while (0)

#define EPI(MR, NP, C0, C1, PC, BX, BY, BZ, LN) do {                           \
    const float sx_ = rdf((BX), (LN));                                         \
    const float sy_ = rdf((BY), (LN));                                         \
    const float sz_ = rdf((BZ), (LN));                                         \
    const float cxf_ = fmaf((float)(C0), 0.2f, 0.1f);   /* VX/2 + 0    */      \
    const float cyf_ = fmaf((float)(C1), 0.2f, -25.5f); /* VY/2 - 25.6 */      \
    const float rnp_ = __builtin_amdgcn_rcpf((float)(NP));                     \
    float u_ = fmaf(sx_, P4s, fmaf(sy_, P5s, sz_ * P6s)) * rnp_;               \
    u_ = fmaf(cxf_, P7s, u_);                                                  \
    u_ = fmaf(cyf_, P8s, u_);                                                  \
    float z_ = (MR) + (shs - u_);                                              \
    z_ = ((NP) < MAXP) ? fmaxf(z_, shs) : z_;                                  \
    if ((PC) < N) out[(size_t)(PC) * 64 + lane] = fmaxf(z_, 0.0f);             \
} while (0)

// one pillar pair: identical math to R14-R19 (proven absmax 0.125)
#define PAIRBODY(G, NPA, C0A, C1A, NPB, C0B, C1B, PA) do {                     \
    const int p0 = cvtpk((G).x, (G).y);                                        \
    const int p1 = cvtpk((G).z, (G).w);                                        \
    const float bx = fold16(sum16((G).x));                                     \
    const float by = fold16(sum16((G).y));                                     \
    const float bz = fold16(sum16((G).z));                                     \
    const int qA0 = rdi(p0, 0),  qA1 = rdi(p1, 0);                             \
    const int qB0 = rdi(p0, 32), qB1 = rdi(p1, 32);                            \
    const int sB0 = swaphalf(p0), sB1 = swaphalf(p1);                          \
    const bool cvA = (pt < (NPA)), cvB = (pt < (NPB));                         \
    FragAB faA, faB;                                                           \
    faA.i[0] = lo32 ? (cvA ? p0  : qA0) : 0;                                   \
    faA.i[1] = lo32 ? (cvA ? p1  : qA1) : 0;                                   \
    faA.i[2] = 0; faA.i[3] = 0;                                                \
    faB.i[0] = lo32 ? (cvB ? sB0 : qB0) : 0;                                   \
    faB.i[1] = lo32 ? (cvB ? sB1 : qB1) : 0;                                   \
    faB.i[2] = 0; faB.i[3] = 0;                                                \
    f32x16 aLA = __builtin_amdgcn_mfma_f32_32x32x16_bf16(faA.v, fbL.v, zacc, 0, 0, 0); \
    f32x16 aHA = __builtin_amdgcn_mfma_f32_32x32x16_bf16(faA.v, fbH.v, zacc, 0, 0, 0); \
    f32x16 aLB = __builtin_amdgcn_mfma_f32_32x32x16_bf16(faB.v, fbL.v, zacc, 0, 0, 0); \
    f32x16 aHB = __builtin_amdgcn_mfma_f32_32x32x16_bf16(faB.v, fbH.v, zacc, 0, 0, 0); \
    const float mrA = mergemax(rmax16(aLA), rmax16(aHA));                      \
    const float mrB = mergemax(rmax16(aLB), rmax16(aHB));                      \
    EPI(mrA, NPA, C0A, C1A, (PA),     bx, by, bz, 0);                          \
    EPI(mrB, NPB, C0B, C1B, (PA) + 1, bx, by, bz, 32);                         \
} while (0)

    // ---- 2 independent pairs, fully unrolled; all loads hoisted ----
    float4 g0, g1;
    int npA0,c0A0,c1A0,npB0,c0B0,c1B0;
    int npA1,c0A1,c1A1,npB1,c0B1,c1B1;
    LOADPAIR(g0, npA0,c0A0,c1A0, npB0,c0B0,c1B0, base + 0);
    LOADPAIR(g1, npA1,c0A1,c1A1, npB1,c0B1,c1B1, base + 2);

    PAIRBODY(g0, npA0,c0A0,c1A0, npB0,c0B0,c1B0, base + 0);
    PAIRBODY(g1, npA1,c0A1,c1A1, npB1,c0B1,c1B1, base + 2);

#undef PAIRBODY
#undef EPI
#undef LOADPAIR
}

extern "C" void kernel_launch(void* const* d_in, const int* in_sizes, int n_in,
                              void* d_out, int out_size, void* d_ws, size_t ws_size,
                              hipStream_t stream) {
    const float* voxels     = (const float*)d_in[0];
    const int*   num_points = (const int*)  d_in[1];
    const int*   coords     = (const int*)  d_in[2];
    const float* W          = (const float*)d_in[3];
    const float* gammav     = (const float*)d_in[4];
    const float* betav      = (const float*)d_in[5];
    const float* rmean      = (const float*)d_in[6];
    const float* rvar       = (const float*)d_in[7];
    float*       out        = (float*)d_out;

    const int N = in_sizes[1];                    // one entry per pillar
    const int per_block = WPB * PPW;              // 16 waves x 4 pillars
    const int blocks = (N + per_block - 1) / per_block;
    pfn_kernel<<<blocks, WPB * 64, 0, stream>>>(voxels, num_points, coords, W,
                                                gammav, betav, rmean, rvar, out, N);
}

// Round 21
// 23.945 us; speedup vs baseline: 1.1325x; 1.1325x over previous
//
#include <hip/hip_runtime.h>
#include <hip/hip_bf16.h>
#include <math.h>

#define MAXP 32
#define PPW  2    // pillars per wave (ONE pair; THE one change: 4 -> 2)
#define WPB  8    // waves per block (proven optimum R19/R20)

typedef __attribute__((ext_vector_type(8)))  short bf16x8;
typedef __attribute__((ext_vector_type(16))) float f32x16;

template <int CTRL>
__device__ __forceinline__ float dppadd(float v) {
    int t = __builtin_amdgcn_update_dpp(0, __float_as_int(v), CTRL, 0xF, 0xF, false);
    return v + __int_as_float(t);
}
// sum within each 16-lane group (HW-verified R6-R20)
__device__ __forceinline__ float sum16(float v) {
    v = dppadd<0xB1>(v);    // xor1
    v = dppadd<0x4E>(v);    // xor2
    v = dppadd<0x141>(v);   // row_half_mirror
    v = dppadd<0x140>(v);   // row_mirror
    return v;
}
// within-32-half full sum from 16-group sums (HW-validated R13/R14)
__device__ __forceinline__ float fold16(float s) {
    auto pr = __builtin_amdgcn_permlane16_swap(__float_as_uint(s),
                                               __float_as_uint(s), false, false);
    return __uint_as_float(pr[0]) + __uint_as_float(pr[1]);
}
__device__ __forceinline__ float rdf(float v, int l) {
    return __int_as_float(__builtin_amdgcn_readlane(__float_as_int(v), l));
}
__device__ __forceinline__ int rdi(int v, int l) {
    return __builtin_amdgcn_readlane(v, l);
}
// HW-validated (R13/R14): permlane32_swap(a,b) -> pr[0]={a.lo,b.lo}, pr[1]={a.hi,b.hi}
__device__ __forceinline__ int swaphalf(int v) {   // other half's word into LO lanes
    auto pr = __builtin_amdgcn_permlane32_swap(v, v, false, false);
    return (int)pr[1];
}
__device__ __forceinline__ float mergemax(float mL, float mH) {
    auto pm = __builtin_amdgcn_permlane32_swap(__float_as_uint(mL),
                                               __float_as_uint(mH), false, false);
    return fmaxf(__uint_as_float(pm[0]), __uint_as_float(pm[1]));
}
// own-channel word -> (lo-half duplicated, hi-half duplicated) across all lanes
__device__ __forceinline__ void bothdup(int own, int& loAll, int& hiAll) {
    auto pr = __builtin_amdgcn_permlane32_swap(own, own, false, false);
    loAll = (int)pr[0];
    hiAll = (int)pr[1];
}
// 1-instruction bf16 pair pack (lo -> low16, hi -> high16); proven R10
__device__ __forceinline__ int cvtpk(float lo, float hi) {
    int r;
    asm("v_cvt_pk_bf16_f32 %0, %1, %2" : "=v"(r) : "v"(lo), "v"(hi));
    return r;
}
__device__ __forceinline__ float rmax16(f32x16 a) {   // max3-fusable tree
    float m1 = fmaxf(fmaxf(a[0], a[1]),  a[2]);
    float m2 = fmaxf(fmaxf(a[3], a[4]),  a[5]);
    float m3 = fmaxf(fmaxf(a[6], a[7]),  a[8]);
    float m4 = fmaxf(fmaxf(a[9], a[10]), a[11]);
    float m5 = fmaxf(fmaxf(a[12],a[13]), a[14]);
    float mm = fmaxf(fmaxf(m1, m2), m3);
    return fmaxf(fmaxf(fmaxf(m4, m5), a[15]), mm);
}

union FragAB { bf16x8 v; int i[4]; };

__global__ __launch_bounds__(WPB * 64) void pfn_kernel(
    const float* __restrict__ voxels,
    const int*   __restrict__ num_points,
    const int*   __restrict__ coords,
    const float* __restrict__ W,
    const float* __restrict__ gammav,
    const float* __restrict__ betav,
    const float* __restrict__ rmean,
    const float* __restrict__ rvar,
    float*       __restrict__ out,
    int N)
{
    const int  lane = threadIdx.x & 63;
    const int  wid  = threadIdx.x >> 6;   // 0..WPB-1
    const int  pt   = lane & 31;          // A-frag row (point slot)
    const bool lo32 = (lane < 32);

    int vz;                               // opaque 0: pins meta loads to VMEM
    asm("v_mov_b32 %0, 0" : "=v"(vz));

    const int base = (blockIdx.x * WPB + wid) * PPW;
    if (base >= N) return;

    // ---- setup: ONE coefficient block (own channel = lane), permlane-duplicated
    //      into both B-frags (content-identical; proven R18/R19) ----
    float P4s, P5s, P6s, P7s, P8s, shs;   // own channel's epilogue coefs
    FragAB fbL, fbH;                      // B-frags: only k=0..3 matter
    {
        const int c = lane;
        float w0=W[c],w1=W[64+c],w2=W[128+c],w3=W[192+c],w4=W[256+c],
              w5=W[320+c],w6=W[384+c],w7=W[448+c],w8=W[512+c];
        float inv = gammav[c] * rsqrtf(rvar[c] + 1e-3f);
        shs = fmaf(-rmean[c], inv, betav[c]);
        float A  =(w0+w4+w7)*inv, B=(w1+w5+w8)*inv, C=(w2+w6)*inv, Dk=w3*inv;
        P4s=w4*inv; P5s=w5*inv; P6s=w6*inv; P7s=w7*inv; P8s=w8*inv;
        const int own0 = cvtpk(A, B);
        const int own1 = cvtpk(C, Dk);
        bothdup(own0, fbL.i[0], fbH.i[0]);
        bothdup(own1, fbL.i[1], fbH.i[1]);
        fbL.i[2]=0; fbL.i[3]=0; fbH.i[2]=0; fbH.i[3]=0;
    }

    const f32x16 zacc = {0,0,0,0,0,0,0,0,0,0,0,0,0,0,0,0};

#define LOADPAIR(G, NPA, C0A, C1A, NPB, C0B, C1B, pA) do {                     \
    const int sA_ = min((pA),     N - 1);                                      \
    const int sB_ = min((pA) + 1, N - 1);                                      \
    const int sel_ = lo32 ? sA_ : sB_;                                         \
    G   = *(const float4*)((const char*)voxels +                               \
                           (size_t)sel_ * 512 + (size_t)pt * 16);              \
    NPA = *(const int*)((const char*)num_points + (size_t)sA_*4  + vz);        \
    C0A = *(const int*)((const char*)coords     + (size_t)sA_*12 + vz);        \
    C1A = *(const int*)((const char*)coords     + (size_t)sA_*12 + 4 + vz);    \
    NPB = *(const int*)((const char*)num_points + (size_t)sB_*4  + vz);        \
    C0B = *(const int*)((const char*)coords     + (size_t)sB_*12 + vz);        \
    C1B = *(const int*)((const char*)coords     + (size_t)sB_*12 + 4 + vz);    \
} while (0)

#define EPI(MR, NP, C0, C1, PC, BX, BY, BZ, LN) do {                           \
    const float sx_ = rdf((BX), (LN));                                         \
    const float sy_ = rdf((BY), (LN));                                         \
    const float sz_ = rdf((BZ), (LN));                                         \
    const float cxf_ = fmaf((float)(C0), 0.2f, 0.1f);   /* VX/2 + 0    */      \
    const float cyf_ = fmaf((float)(C1), 0.2f, -25.5f); /* VY/2 - 25.6 */      \
    const float rnp_ = __builtin_amdgcn_rcpf((float)(NP));                     \
    float u_ = fmaf(sx_, P4s, fmaf(sy_, P5s, sz_ * P6s)) * rnp_;               \
    u_ = fmaf(cxf_, P7s, u_);                                                  \
    u_ = fmaf(cyf_, P8s, u_);                                                  \
    float z_ = (MR) + (shs - u_);                                              \
    z_ = ((NP) < MAXP) ? fmaxf(z_, shs) : z_;                                  \
    if ((PC) < N) out[(size_t)(PC) * 64 + lane] = fmaxf(z_, 0.0f);             \
} while (0)

// one pillar pair: identical math to R14-R20 (proven absmax 0.125)
#define PAIRBODY(G, NPA, C0A, C1A, NPB, C0B, C1B, PA) do {                     \
    const int p0 = cvtpk((G).x, (G).y);                                        \
    const int p1 = cvtpk((G).z, (G).w);                                        \
    const float bx = fold16(sum16((G).x));                                     \
    const float by = fold16(sum16((G).y));                                     \
    const float bz = fold16(sum16((G).z));                                     \
    const int qA0 = rdi(p0, 0),  qA1 = rdi(p1, 0);                             \
    const int qB0 = rdi(p0, 32), qB1 = rdi(p1, 32);                            \
    const int sB0 = swaphalf(p0), sB1 = swaphalf(p1);                          \
    const bool cvA = (pt < (NPA)), cvB = (pt < (NPB));                         \
    FragAB faA, faB;                                                           \
    faA.i[0] = lo32 ? (cvA ? p0  : qA0) : 0;                                   \
    faA.i[1] = lo32 ? (cvA ? p1  : qA1) : 0;                                   \
    faA.i[2] = 0; faA.i[3] = 0;                                                \
    faB.i[0] = lo32 ? (cvB ? sB0 : qB0) : 0;                                   \
    faB.i[1] = lo32 ? (cvB ? sB1 : qB1) : 0;                                   \
    faB.i[2] = 0; faB.i[3] = 0;                                                \
    f32x16 aLA = __builtin_amdgcn_mfma_f32_32x32x16_bf16(faA.v, fbL.v, zacc, 0, 0, 0); \
    f32x16 aHA = __builtin_amdgcn_mfma_f32_32x32x16_bf16(faA.v, fbH.v, zacc, 0, 0, 0); \
    f32x16 aLB = __builtin_amdgcn_mfma_f32_32x32x16_bf16(faB.v, fbL.v, zacc, 0, 0, 0); \
    f32x16 aHB = __builtin_amdgcn_mfma_f32_32x32x16_bf16(faB.v, fbH.v, zacc, 0, 0, 0); \
    const float mrA = mergemax(rmax16(aLA), rmax16(aHA));                      \
    const float mrB = mergemax(rmax16(aLB), rmax16(aHB));                      \
    EPI(mrA, NPA, C0A, C1A, (PA),     bx, by, bz, 0);                          \
    EPI(mrB, NPB, C0B, C1B, (PA) + 1, bx, by, bz, 32);                         \
} while (0)

    // ---- exactly one pair per wave (span-minimal at proven WPB=8) ----
    float4 g0;
    int npA0,c0A0,c1A0,npB0,c0B0,c1B0;
    LOADPAIR(g0, npA0,c0A0,c1A0, npB0,c0B0,c1B0, base);
    PAIRBODY(g0, npA0,c0A0,c1A0, npB0,c0B0,c1B0, base);

#undef PAIRBODY
#undef EPI
#undef LOADPAIR
}

extern "C" void kernel_launch(void* const* d_in, const int* in_sizes, int n_in,
                              void* d_out, int out_size, void* d_ws, size_t ws_size,
                              hipStream_t stream) {
    const float* voxels     = (const float*)d_in[0];
    const int*   num_points = (const int*)  d_in[1];
    const int*   coords     = (const int*)  d_in[2];
    const float* W          = (const float*)d_in[3];
    const float* gammav     = (const float*)d_in[4];
    const float* betav      = (const float*)d_in[5];
    const float* rmean      = (const float*)d_in[6];
    const float* rvar       = (const float*)d_in[7];
    float*       out        = (float*)d_out;

    const int N = in_sizes[1];                    // one entry per pillar
    const int per_block = WPB * PPW;              // 8 waves x 2 pillars
    const int blocks = (N + per_block - 1) / per_block;
    pfn_kernel<<<blocks, WPB * 64, 0, stream>>>(voxels, num_points, coords, W,
                                                gammav, betav, rmean, rvar, out, N);
}